// Round 6
// baseline (2509.243 us; speedup 1.0000x reference)
//
#include <hip/hip_runtime.h>
#include <hip/hip_bf16.h>
#include <stdint.h>

#define KDIM 1024
#define NROW 4096
#define NCOL 4096
#define INFV 1e30f
#define INFBITS 0x7149F2CAu     // bits of 1e30f
#define BM 128
#define BK 32

#define NWG    16               // 16 WGs x 1 wave x 64 lanes x 4 cols = 4096 columns
#define NBLKS  260              // 16-step blocks: covers tj 0..4159 (NROW+63=4159)
#define SKROWS 4160             // skewed cost rows

typedef __bf16 bf16x8 __attribute__((ext_vector_type(8)));
typedef float f32x4 __attribute__((ext_vector_type(4)));
typedef unsigned u32x2 __attribute__((ext_vector_type(2)));

__device__ __forceinline__ unsigned short f2bf(float f) {
    __hip_bfloat16 h = __float2bfloat16(f);
    return *reinterpret_cast<unsigned short*>(&h);
}

// ---------------------------------------------------------------------------
// Kernel 1: row-normalize both trajectories, emit bf16
// ---------------------------------------------------------------------------
__global__ __launch_bounds__(256) void normalize_bf16(
    const float* __restrict__ t1, const float* __restrict__ t2,
    unsigned short* __restrict__ o1, unsigned short* __restrict__ o2)
{
    int b = blockIdx.x;
    int t = threadIdx.x;
    const float* src;
    unsigned short* dst;
    if (b < NROW) { src = t1 + (size_t)b * KDIM;          dst = o1 + (size_t)b * KDIM; }
    else          { src = t2 + (size_t)(b - NROW) * KDIM; dst = o2 + (size_t)(b - NROW) * KDIM; }

    float4 v = reinterpret_cast<const float4*>(src)[t];
    float ss = v.x * v.x + v.y * v.y + v.z * v.z + v.w * v.w;
    #pragma unroll
    for (int d = 32; d >= 1; d >>= 1) ss += __shfl_xor(ss, d, 64);

    __shared__ float wsum[4];
    int wave = t >> 6;
    if ((t & 63) == 0) wsum[wave] = ss;
    __syncthreads();
    float inv = 1.0f / (sqrtf(wsum[0] + wsum[1] + wsum[2] + wsum[3]) + 1e-8f);

    ushort4 o;
    o.x = f2bf(v.x * inv);
    o.y = f2bf(v.y * inv);
    o.z = f2bf(v.z * inv);
    o.w = f2bf(v.w * inv);
    reinterpret_cast<ushort4*>(dst)[t] = o;
}

// ---------------------------------------------------------------------------
// Kernel 2: skewed cost: skew[i + ((j>>2)&63)][j] = 1 - dot(t1n[i], t2n[j])
// ---------------------------------------------------------------------------
__global__ __launch_bounds__(256) void gemm_cost(
    const unsigned short* __restrict__ A,
    const unsigned short* __restrict__ B,
    unsigned short* __restrict__ Cs)    // skewed [SKROWS][4096]
{
    __shared__ __align__(16) unsigned short As[BM * BK];
    __shared__ __align__(16) unsigned short Bs[BM * BK];

    int t    = threadIdx.x;
    int lane = t & 63;
    int wave = t >> 6;
    int i0   = blockIdx.y * BM;
    int j0   = blockIdx.x * BM;

    f32x4 acc[4][4];
    f32x4 zero = {0.f, 0.f, 0.f, 0.f};
    #pragma unroll
    for (int m = 0; m < 4; ++m)
        #pragma unroll
        for (int n = 0; n < 4; ++n) acc[m][n] = zero;

    int frow = lane & 15;
    int fk   = (lane >> 4) * 8;
    int wr   = (wave >> 1) * 64;
    int wc   = (wave & 1) * 64;

    int srow = t >> 2;
    int scb  = (t & 3) * 8;

    uint4 ra0, ra1, rb0, rb1;
    {
        ra0 = *reinterpret_cast<const uint4*>(A + (size_t)(i0 + srow) * KDIM + scb);
        ra1 = *reinterpret_cast<const uint4*>(A + (size_t)(i0 + 64 + srow) * KDIM + scb);
        rb0 = *reinterpret_cast<const uint4*>(B + (size_t)(j0 + srow) * KDIM + scb);
        rb1 = *reinterpret_cast<const uint4*>(B + (size_t)(j0 + 64 + srow) * KDIM + scb);
    }

    for (int k0 = 0; k0 < KDIM; k0 += BK) {
        __syncthreads();
        *reinterpret_cast<uint4*>(As + (size_t)t * 8)         = ra0;
        *reinterpret_cast<uint4*>(As + (size_t)(256 + t) * 8) = ra1;
        *reinterpret_cast<uint4*>(Bs + (size_t)t * 8)         = rb0;
        *reinterpret_cast<uint4*>(Bs + (size_t)(256 + t) * 8) = rb1;
        __syncthreads();

        if (k0 + BK < KDIM) {
            int kn = k0 + BK;
            ra0 = *reinterpret_cast<const uint4*>(A + (size_t)(i0 + srow) * KDIM + kn + scb);
            ra1 = *reinterpret_cast<const uint4*>(A + (size_t)(i0 + 64 + srow) * KDIM + kn + scb);
            rb0 = *reinterpret_cast<const uint4*>(B + (size_t)(j0 + srow) * KDIM + kn + scb);
            rb1 = *reinterpret_cast<const uint4*>(B + (size_t)(j0 + 64 + srow) * KDIM + kn + scb);
        }

        bf16x8 af[4], bfr[4];
        #pragma unroll
        for (int m = 0; m < 4; ++m)
            af[m] = *reinterpret_cast<const bf16x8*>(As + (wr + m * 16 + frow) * BK + fk);
        #pragma unroll
        for (int n = 0; n < 4; ++n)
            bfr[n] = *reinterpret_cast<const bf16x8*>(Bs + (wc + n * 16 + frow) * BK + fk);

        #pragma unroll
        for (int m = 0; m < 4; ++m)
            #pragma unroll
            for (int n = 0; n < 4; ++n)
                acc[m][n] = __builtin_amdgcn_mfma_f32_16x16x32_bf16(af[m], bfr[n], acc[m][n], 0, 0, 0);
    }

    int crow = (lane >> 4) * 4;
    int ccol = lane & 15;
    #pragma unroll
    for (int n = 0; n < 4; ++n) {
        const int j  = j0 + wc + n * 16 + ccol;
        const int Lj = (j >> 2) & 63;
        #pragma unroll
        for (int m = 0; m < 4; ++m) {
            const int ibase = i0 + wr + m * 16 + crow;
            #pragma unroll
            for (int q = 0; q < 4; ++q)
                Cs[(size_t)(ibase + q + Lj) * NCOL + j] = f2bf(1.0f - acc[m][n][q]);
        }
    }
}

// ---------------------------------------------------------------------------
// ring_init: prefill the dummy segment (index NWG-1) read by WG 0.
// ---------------------------------------------------------------------------
__global__ __launch_bounds__(256) void ring_init(unsigned long long* __restrict__ ring)
{
    int i = blockIdx.x * 256 + threadIdx.x;
    ring[(size_t)(NWG - 1) * NROW + i] =
        ((unsigned long long)INFBITS << 32) | (unsigned)(i + 1);
}

// ---------------------------------------------------------------------------
// Kernel 3: systolic DTW, full manual VMEM control.
// Per 16-step block: 16 asm cost loads + 1 asm ring load (per-lane, 16 slots)
// double-banked in NAMED registers; one s_waitcnt vmcnt(33) per block whose
// "+v" in-out bindings pin consumers after the wait. Exactly one store per
// step (real ring slot or dummy sink) keeps the vmcnt count uniform.
// ---------------------------------------------------------------------------
__global__ __launch_bounds__(64, 1) void dtw_systolic(
    const unsigned short* __restrict__ cost,   // skewed [SKROWS][4096]
    unsigned long long* __restrict__ ring,     // [NWG][NROW]; seg NWG-1 = dummy
    unsigned long long* __restrict__ dsink,    // 64-slot dummy store sink
    float* __restrict__ out)
{
    const int w    = blockIdx.x;
    const int lane = threadIdx.x;
    const char* cb = (const char*)cost;
    const unsigned colByte = (unsigned)(w * 64 + lane) * 8u;   // 4 bf16 = 8 B
    const unsigned loA = ((unsigned)lane << 13) + colByte;            // row 0
    const unsigned hiA = ((unsigned)(4095 + lane) << 13) + colByte;   // row 4095
    const char* rbase = (const char*)(ring + (size_t)((w == 0) ? (NWG - 1) : (w - 1)) * NROW);
    unsigned long long* wseg = ring + (size_t)w * NROW;
    const bool last = (w == NWG - 1);
    const unsigned lmin = lane > 15 ? 15u : (unsigned)lane;

    float pd0 = INFV, pd1 = INFV, pd2 = INFV, pd3 = INFV;
    float lprev = (w == 0 && lane == 0) ? 0.0f : INFV;
    float d3p = INFV;
    unsigned ansb = 0;

    u32x2 qa0, qa1, qa2, qa3, qa4, qa5, qa6, qa7,
          qa8, qa9, qa10, qa11, qa12, qa13, qa14, qa15;
    u32x2 qb0, qb1, qb2, qb3, qb4, qb5, qb6, qb7,
          qb8, qb9, qb10, qb11, qb12, qb13, qb14, qb15;
    u32x2 ra, rb;

#define IC(Q, TJ) { unsigned a_ = ((unsigned)(TJ) << 13) + colByte; \
        a_ = a_ < loA ? loA : (a_ > hiA ? hiA : a_); \
        asm volatile("global_load_dwordx2 %0, %1, %2" : "=v"(Q) : "v"(a_), "s"(cb)); }

#define IR(R, BLK) { unsigned ro_ = (unsigned)((BLK) * 16) + lmin; \
        ro_ = (ro_ > 4095u ? 4095u : ro_) * 8u; \
        asm volatile("global_load_dwordx2 %0, %1, %2 sc0 sc1" : "=v"(R) : "v"(ro_), "s"(rbase)); }

#define ISSUE_BANK(P, R, BLK) { \
        IC(P##0,  (BLK)*16+0)  IC(P##1,  (BLK)*16+1)  IC(P##2,  (BLK)*16+2)  IC(P##3,  (BLK)*16+3) \
        IC(P##4,  (BLK)*16+4)  IC(P##5,  (BLK)*16+5)  IC(P##6,  (BLK)*16+6)  IC(P##7,  (BLK)*16+7) \
        IC(P##8,  (BLK)*16+8)  IC(P##9,  (BLK)*16+9)  IC(P##10, (BLK)*16+10) IC(P##11, (BLK)*16+11) \
        IC(P##12, (BLK)*16+12) IC(P##13, (BLK)*16+13) IC(P##14, (BLK)*16+14) IC(P##15, (BLK)*16+15) \
        IR(R, BLK) }

#define WAIT_A() asm volatile("s_waitcnt vmcnt(33)" \
        : "+v"(qa0),"+v"(qa1),"+v"(qa2),"+v"(qa3),"+v"(qa4),"+v"(qa5),"+v"(qa6),"+v"(qa7), \
          "+v"(qa8),"+v"(qa9),"+v"(qa10),"+v"(qa11),"+v"(qa12),"+v"(qa13),"+v"(qa14),"+v"(qa15), \
          "+v"(ra) :: "memory")
#define WAIT_B() asm volatile("s_waitcnt vmcnt(33)" \
        : "+v"(qb0),"+v"(qb1),"+v"(qb2),"+v"(qb3),"+v"(qb4),"+v"(qb5),"+v"(qb6),"+v"(qb7), \
          "+v"(qb8),"+v"(qb9),"+v"(qb10),"+v"(qb11),"+v"(qb12),"+v"(qb13),"+v"(qb14),"+v"(qb15), \
          "+v"(rb) :: "memory")

#define CHECKR(R, BLK) { \
        unsigned sc_ = (unsigned)((BLK) * 16) + lmin; \
        sc_ = sc_ > 4095u ? 4095u : sc_; \
        const unsigned expt_ = sc_ + 1u; \
        while (__ballot(R.x == expt_) != ~0ull) { \
            const unsigned ro_ = sc_ * 8u; \
            asm volatile("global_load_dwordx2 %0, %1, %2 sc0 sc1\n\ts_waitcnt vmcnt(0)" \
                : "=v"(R) : "v"(ro_), "s"(rbase) : "memory"); \
            __builtin_amdgcn_sched_barrier(0); \
        } }

#define STEPK(Q, R, TJ, K) { \
        const unsigned vb_ = (unsigned)__builtin_amdgcn_readlane((int)R.y, K); \
        const unsigned lcb_ = (unsigned)__builtin_amdgcn_update_dpp( \
            (int)vb_, (int)__float_as_uint(d3p), 0x138, 0xf, 0xf, false); \
        const float lcur = __uint_as_float(lcb_); \
        const float c0 = __uint_as_float(Q.x << 16); \
        const float c1 = __uint_as_float(Q.x & 0xffff0000u); \
        const float c2 = __uint_as_float(Q.y << 16); \
        const float c3 = __uint_as_float(Q.y & 0xffff0000u); \
        const float e0 = c0 + fminf(fminf(lcur, pd0), lprev); \
        const float e1 = c1 + fminf(fminf(e0, pd1), pd0); \
        const float e2 = c2 + fminf(fminf(e1, pd2), pd1); \
        const float e3 = c3 + fminf(fminf(e2, pd3), pd2); \
        const int rp_ = (TJ) - 63; \
        const unsigned long long pk_ = \
            ((unsigned long long)__float_as_uint(e3) << 32) | (unsigned)(rp_ + 1); \
        unsigned long long* sp_ = (lane == 63 && (unsigned)rp_ < 4096u && !last) \
            ? (wseg + rp_) : (dsink + lane); \
        __hip_atomic_store(sp_, pk_, __ATOMIC_RELAXED, __HIP_MEMORY_SCOPE_AGENT); \
        ansb = ((TJ) == NROW - 1 + 63) ? __float_as_uint(e3) : ansb; \
        lprev = lcur; d3p = e3; \
        pd0 = e0; pd1 = e1; pd2 = e2; pd3 = e3; }

#define STEP16(P, R, BLK) { \
        STEPK(P##0,  R, (BLK)*16+0,  0)  STEPK(P##1,  R, (BLK)*16+1,  1) \
        STEPK(P##2,  R, (BLK)*16+2,  2)  STEPK(P##3,  R, (BLK)*16+3,  3) \
        STEPK(P##4,  R, (BLK)*16+4,  4)  STEPK(P##5,  R, (BLK)*16+5,  5) \
        STEPK(P##6,  R, (BLK)*16+6,  6)  STEPK(P##7,  R, (BLK)*16+7,  7) \
        STEPK(P##8,  R, (BLK)*16+8,  8)  STEPK(P##9,  R, (BLK)*16+9,  9) \
        STEPK(P##10, R, (BLK)*16+10, 10) STEPK(P##11, R, (BLK)*16+11, 11) \
        STEPK(P##12, R, (BLK)*16+12, 12) STEPK(P##13, R, (BLK)*16+13, 13) \
        STEPK(P##14, R, (BLK)*16+14, 14) STEPK(P##15, R, (BLK)*16+15, 15) }

    // prologue: bank A for block 0, then 16 dummy stores to equalize the
    // per-block vmcnt issue pattern (17 loads + 16 stores).
    ISSUE_BANK(qa, ra, 0)
    #pragma unroll
    for (int k = 0; k < 16; ++k)
        __hip_atomic_store(dsink + lane, (unsigned long long)k,
                           __ATOMIC_RELAXED, __HIP_MEMORY_SCOPE_AGENT);

    for (int b = 0; b < NBLKS; b += 2) {
        ISSUE_BANK(qb, rb, b + 1)
        WAIT_A();
        CHECKR(ra, b)
        STEP16(qa, ra, b)

        ISSUE_BANK(qa, ra, b + 2)
        WAIT_B();
        CHECKR(rb, b + 1)
        STEP16(qb, rb, b + 1)
    }

#undef IC
#undef IR
#undef ISSUE_BANK
#undef WAIT_A
#undef WAIT_B
#undef CHECKR
#undef STEPK
#undef STEP16

    if (last && lane == 63) out[0] = 1.0f / (1.0f + __uint_as_float(ansb));
}

// ---------------------------------------------------------------------------
extern "C" void kernel_launch(void* const* d_in, const int* in_sizes, int n_in,
                              void* d_out, int out_size, void* d_ws, size_t ws_size,
                              hipStream_t stream)
{
    const float* t1 = (const float*)d_in[0];
    const float* t2 = (const float*)d_in[1];
    float* out = (float*)d_out;

    char* ws = (char*)d_ws;
    unsigned short* t1n  = (unsigned short*)ws;                                   // 8 MB
    unsigned short* t2n  = (unsigned short*)(ws + (size_t)NROW * KDIM * 2);       // 8 MB
    unsigned short* skew = (unsigned short*)(ws + (size_t)16 * 1024 * 1024);      // 34.1 MB
    unsigned long long* ring  = (unsigned long long*)(ws + (size_t)52 * 1024 * 1024); // 512 KB
    unsigned long long* dsink = (unsigned long long*)(ws + (size_t)53 * 1024 * 1024); // 512 B

    // clear real segments 0..NWG-2, prefill dummy segment NWG-1
    hipMemsetAsync(ring, 0, (size_t)(NWG - 1) * NROW * 8, stream);
    ring_init<<<NROW / 256, 256, 0, stream>>>(ring);
    normalize_bf16<<<2 * NROW, 256, 0, stream>>>(t1, t2, t1n, t2n);
    gemm_cost<<<dim3(NCOL / BM, NROW / BM), 256, 0, stream>>>(t1n, t2n, skew);
    dtw_systolic<<<NWG, 64, 0, stream>>>(skew, ring, dsink, out);
}

// Round 8
// 712.696 us; speedup vs baseline: 3.5208x; 3.5208x over previous
//
#include <hip/hip_runtime.h>
#include <hip/hip_bf16.h>
#include <stdint.h>

#define KDIM 1024
#define NROW 4096
#define NCOL 4096
#define INFV 1e30f
#define INFBITS 0x7149F2CAu     // bits of 1e30f
#define BM 128
#define BK 32

#define NWG    16               // 16 WGs x 1 wave x 64 lanes x 4 cols = 4096 columns
#define SKROWS 4160             // skewed cost rows
#define TOTBLKS 261             // 16-step blocks; block 260 only flushes ring stores

typedef __bf16 bf16x8 __attribute__((ext_vector_type(8)));
typedef float f32x4 __attribute__((ext_vector_type(4)));

#define CFENCE asm volatile("" ::: "memory")

__device__ __forceinline__ unsigned short f2bf(float f) {
    __hip_bfloat16 h = __float2bfloat16(f);
    return *reinterpret_cast<unsigned short*>(&h);
}

__device__ __forceinline__ void gll16(const void* gsrc, void* ldst) {
    __builtin_amdgcn_global_load_lds(
        (const __attribute__((address_space(1))) void*)gsrc,
        (__attribute__((address_space(3))) void*)ldst, 16, 0, 0);
}

// ---------------------------------------------------------------------------
// Kernel 1: row-normalize both trajectories, emit bf16
// ---------------------------------------------------------------------------
__global__ __launch_bounds__(256) void normalize_bf16(
    const float* __restrict__ t1, const float* __restrict__ t2,
    unsigned short* __restrict__ o1, unsigned short* __restrict__ o2)
{
    int b = blockIdx.x;
    int t = threadIdx.x;
    const float* src;
    unsigned short* dst;
    if (b < NROW) { src = t1 + (size_t)b * KDIM;          dst = o1 + (size_t)b * KDIM; }
    else          { src = t2 + (size_t)(b - NROW) * KDIM; dst = o2 + (size_t)(b - NROW) * KDIM; }

    float4 v = reinterpret_cast<const float4*>(src)[t];
    float ss = v.x * v.x + v.y * v.y + v.z * v.z + v.w * v.w;
    #pragma unroll
    for (int d = 32; d >= 1; d >>= 1) ss += __shfl_xor(ss, d, 64);

    __shared__ float wsum[4];
    int wave = t >> 6;
    if ((t & 63) == 0) wsum[wave] = ss;
    __syncthreads();
    float inv = 1.0f / (sqrtf(wsum[0] + wsum[1] + wsum[2] + wsum[3]) + 1e-8f);

    ushort4 o;
    o.x = f2bf(v.x * inv);
    o.y = f2bf(v.y * inv);
    o.z = f2bf(v.z * inv);
    o.w = f2bf(v.w * inv);
    reinterpret_cast<ushort4*>(dst)[t] = o;
}

// ---------------------------------------------------------------------------
// Kernel 2: skewed cost: skew[i + ((j>>2)&63)][j] = 1 - dot(t1n[i], t2n[j])
// ---------------------------------------------------------------------------
__global__ __launch_bounds__(256) void gemm_cost(
    const unsigned short* __restrict__ A,
    const unsigned short* __restrict__ B,
    unsigned short* __restrict__ Cs)    // skewed [SKROWS][4096]
{
    __shared__ __align__(16) unsigned short As[BM * BK];
    __shared__ __align__(16) unsigned short Bs[BM * BK];

    int t    = threadIdx.x;
    int lane = t & 63;
    int wave = t >> 6;
    int i0   = blockIdx.y * BM;
    int j0   = blockIdx.x * BM;

    f32x4 acc[4][4];
    f32x4 zero = {0.f, 0.f, 0.f, 0.f};
    #pragma unroll
    for (int m = 0; m < 4; ++m)
        #pragma unroll
        for (int n = 0; n < 4; ++n) acc[m][n] = zero;

    int frow = lane & 15;
    int fk   = (lane >> 4) * 8;
    int wr   = (wave >> 1) * 64;
    int wc   = (wave & 1) * 64;

    int srow = t >> 2;
    int scb  = (t & 3) * 8;

    uint4 ra0, ra1, rb0, rb1;
    {
        ra0 = *reinterpret_cast<const uint4*>(A + (size_t)(i0 + srow) * KDIM + scb);
        ra1 = *reinterpret_cast<const uint4*>(A + (size_t)(i0 + 64 + srow) * KDIM + scb);
        rb0 = *reinterpret_cast<const uint4*>(B + (size_t)(j0 + srow) * KDIM + scb);
        rb1 = *reinterpret_cast<const uint4*>(B + (size_t)(j0 + 64 + srow) * KDIM + scb);
    }

    for (int k0 = 0; k0 < KDIM; k0 += BK) {
        __syncthreads();
        *reinterpret_cast<uint4*>(As + (size_t)t * 8)         = ra0;
        *reinterpret_cast<uint4*>(As + (size_t)(256 + t) * 8) = ra1;
        *reinterpret_cast<uint4*>(Bs + (size_t)t * 8)         = rb0;
        *reinterpret_cast<uint4*>(Bs + (size_t)(256 + t) * 8) = rb1;
        __syncthreads();

        if (k0 + BK < KDIM) {
            int kn = k0 + BK;
            ra0 = *reinterpret_cast<const uint4*>(A + (size_t)(i0 + srow) * KDIM + kn + scb);
            ra1 = *reinterpret_cast<const uint4*>(A + (size_t)(i0 + 64 + srow) * KDIM + kn + scb);
            rb0 = *reinterpret_cast<const uint4*>(B + (size_t)(j0 + srow) * KDIM + kn + scb);
            rb1 = *reinterpret_cast<const uint4*>(B + (size_t)(j0 + 64 + srow) * KDIM + kn + scb);
        }

        bf16x8 af[4], bfr[4];
        #pragma unroll
        for (int m = 0; m < 4; ++m)
            af[m] = *reinterpret_cast<const bf16x8*>(As + (wr + m * 16 + frow) * BK + fk);
        #pragma unroll
        for (int n = 0; n < 4; ++n)
            bfr[n] = *reinterpret_cast<const bf16x8*>(Bs + (wc + n * 16 + frow) * BK + fk);

        #pragma unroll
        for (int m = 0; m < 4; ++m)
            #pragma unroll
            for (int n = 0; n < 4; ++n)
                acc[m][n] = __builtin_amdgcn_mfma_f32_16x16x32_bf16(af[m], bfr[n], acc[m][n], 0, 0, 0);
    }

    int crow = (lane >> 4) * 4;
    int ccol = lane & 15;
    #pragma unroll
    for (int n = 0; n < 4; ++n) {
        const int j  = j0 + wc + n * 16 + ccol;
        const int Lj = (j >> 2) & 63;
        #pragma unroll
        for (int m = 0; m < 4; ++m) {
            const int ibase = i0 + wr + m * 16 + crow;
            #pragma unroll
            for (int q = 0; q < 4; ++q)
                Cs[(size_t)(ibase + q + Lj) * NCOL + j] = f2bf(1.0f - acc[m][n][q]);
        }
    }
}

// ---------------------------------------------------------------------------
// ring_init: prefill the dummy segment (index NWG) read by WG 0:
// tag = row+1 (always valid), value = +INF.
// ---------------------------------------------------------------------------
__global__ __launch_bounds__(256) void ring_init(unsigned long long* __restrict__ ring)
{
    int i = blockIdx.x * 256 + threadIdx.x;
    ring[(size_t)NWG * NROW + i] =
        ((unsigned long long)INFBITS << 32) | (unsigned)(i + 1);
}

// ---------------------------------------------------------------------------
// Kernel 3: systolic DTW. Pipeline state lives in LDS + the vmcnt counter.
// Per 16-step block (order pinned by CFENCE): 8x global_load_lds_dwordx4
// (cost rows -> 8KB LDS slot, issued 4 blocks ahead), 1 ring atomic load
// (16 slots via lanes 0-15, 6-block rotation), 1 ring store (real rows or
// per-WG dummy -> uniform count). One s_waitcnt vmcnt(42) = 4 blocks + 2 ops
// in flight. Steps: plain-HIP ds_read (compiler-scheduled lgkmcnt), readlane
// + DPP wave_shr boundary injection, 2-dep-op/cell min-plus chain.
// ---------------------------------------------------------------------------
__global__ __launch_bounds__(64, 1) void dtw_systolic(
    const unsigned short* __restrict__ cost,   // skewed [SKROWS][4096]
    unsigned long long* __restrict__ ring,     // [NWG+1][4096] + garb area
    float* __restrict__ out)
{
    __shared__ __align__(16) unsigned char clds[8 * 8192];
    __shared__ float outbox[2][16];
    __shared__ float odump[16];

    const int w    = blockIdx.x;
    const int lane = threadIdx.x;
    const char* skewb = (const char*)cost;
    const unsigned long long* rseg = ring + (size_t)((w == 0) ? NWG : (w - 1)) * NROW;
    unsigned long long* wseg = ring + (size_t)w * NROW;
    unsigned long long* garb = ring + (size_t)(NWG + 1) * NROW + w * 64;
    const bool lastwg = (w == NWG - 1);
    const unsigned lmin = (lane < 16) ? (unsigned)lane : 15u;

    float pd0 = INFV, pd1 = INFV, pd2 = INFV, pd3 = INFV;
    float lprev = (w == 0 && lane == 0) ? 0.0f : INFV;  // diag seed (DP origin)
    float d3p = INFV;

#define GLLBLK(BI) { \
    const int slot_ = (BI) & 7; \
    _Pragma("unroll") \
    for (int g_ = 0; g_ < 8; ++g_) { \
        int sr_ = 16 * (BI) + 2 * g_ + (lane >> 5); \
        if (sr_ > SKROWS - 1) sr_ = SKROWS - 1; \
        gll16(skewb + (size_t)sr_ * 8192 + (w * 512) + ((lane & 31) << 4), \
              clds + slot_ * 8192 + g_ * 1024); \
    } }

#define RINGLD(DST, BI) { \
    unsigned sl_ = 16u * (unsigned)(BI) + lmin; \
    if (sl_ > 4095u) sl_ = 4095u; \
    DST = __hip_atomic_load(rseg + sl_, __ATOMIC_RELAXED, __HIP_MEMORY_SCOPE_AGENT); }

#define DUMMYST { \
    if (lane < 16) \
        __hip_atomic_store(garb + lane, 0ull, __ATOMIC_RELAXED, __HIP_MEMORY_SCOPE_AGENT); }

#define DSTEP(K) { \
    const uint2 cu = *reinterpret_cast<const uint2*>(clds + slotoff + (K) * 512 + (lane << 3)); \
    const unsigned rbK = (unsigned)__builtin_amdgcn_readlane(rvhi, (K)); \
    const float lcur = __uint_as_float((unsigned)__builtin_amdgcn_update_dpp( \
        (int)rbK, (int)__float_as_uint(d3p), 0x138, 0xf, 0xf, false)); \
    const float c0 = __uint_as_float(cu.x << 16); \
    const float c1 = __uint_as_float(cu.x & 0xffff0000u); \
    const float c2 = __uint_as_float(cu.y << 16); \
    const float c3 = __uint_as_float(cu.y & 0xffff0000u); \
    const float n0 = c0 + fminf(pd0, lprev); \
    const float n1 = c1 + fminf(pd1, pd0); \
    const float n2 = c2 + fminf(pd2, pd1); \
    const float n3 = c3 + fminf(pd3, pd2); \
    const float e0 = fminf(lcur + c0, n0); \
    const float e1 = fminf(e0 + c1, n1); \
    const float e2 = fminf(e1 + c2, n2); \
    const float e3 = fminf(e2 + c3, n3); \
    op[K] = e3; \
    lprev = lcur; d3p = e3; \
    pd0 = e0; pd1 = e1; pd2 = e2; pd3 = e3; }

    unsigned long long rv0, rv1, rv2, rv3, rv4, rv5;

    // prologue: R0,R1 at queue head, then 4 "fake blocks" with the exact
    // steady-state issue pattern (G x8, R, S) so vmcnt(42) is uniform.
    RINGLD(rv0, 0) RINGLD(rv1, 1)
    CFENCE;
    GLLBLK(0) CFENCE; RINGLD(rv2, 2) CFENCE; DUMMYST CFENCE;
    GLLBLK(1) CFENCE; RINGLD(rv3, 3) CFENCE; DUMMYST CFENCE;
    GLLBLK(2) CFENCE; RINGLD(rv4, 4) CFENCE; DUMMYST CFENCE;
    GLLBLK(3) CFENCE; RINGLD(rv5, 5) CFENCE; DUMMYST CFENCE;

    #pragma unroll 1
    for (int ib = 0; ib < TOTBLKS; ++ib) {
        GLLBLK(ib + 4)
        CFENCE;
        unsigned long long rvN;
        RINGLD(rvN, ib + 6)
        CFENCE;
        {   // outgoing boundary rows from block ib-1 (real slots or dummy)
            float bv = 0.0f;
            int r = -1;
            bool valid = false;
            if (ib >= 1) {
                bv = outbox[(ib - 1) & 1][lmin];
                r = 16 * (ib - 1) + lane - 63;
                valid = (lane < 16) && (r >= 0) && (r < NROW) && !lastwg;
            }
            unsigned long long* sp = valid ? (wseg + r) : (garb + (lane & 15));
            const unsigned long long pk =
                ((unsigned long long)__float_as_uint(bv) << 32) | (unsigned)(r + 1);
            if (lane < 16)
                __hip_atomic_store(sp, pk, __ATOMIC_RELAXED, __HIP_MEMORY_SCOPE_AGENT);
        }
        CFENCE;
        asm volatile("s_waitcnt vmcnt(42)" ::: "memory");

        if (ib < 256) {   // consume ring block ib (startup transient only polls)
            const unsigned expt = 16u * (unsigned)ib + lmin + 1u;
            while (__ballot((unsigned)rv0 == expt) != ~0ull) {
                rv0 = __hip_atomic_load(rseg + 16u * (unsigned)ib + lmin,
                                        __ATOMIC_RELAXED, __HIP_MEMORY_SCOPE_AGENT);
            }
        }

        const unsigned slotoff = ((unsigned)ib & 7u) * 8192u;
        const int rvhi = (int)(unsigned)(rv0 >> 32);
        float* op = (lane == 63) ? &outbox[ib & 1][0] : odump;

        DSTEP(0)  DSTEP(1)  DSTEP(2)  DSTEP(3)
        DSTEP(4)  DSTEP(5)  DSTEP(6)  DSTEP(7)
        DSTEP(8)  DSTEP(9)  DSTEP(10) DSTEP(11)
        DSTEP(12) DSTEP(13) DSTEP(14) DSTEP(15)

        rv0 = rv1; rv1 = rv2; rv2 = rv3; rv3 = rv4; rv4 = rv5; rv5 = rvN;
    }

#undef GLLBLK
#undef RINGLD
#undef DUMMYST
#undef DSTEP

    // D[4095][4095] was written by lane 63 at step 4158 = block 259, K=14.
    if (lastwg && lane == 0) out[0] = 1.0f / (1.0f + outbox[1][14]);
}

// ---------------------------------------------------------------------------
extern "C" void kernel_launch(void* const* d_in, const int* in_sizes, int n_in,
                              void* d_out, int out_size, void* d_ws, size_t ws_size,
                              hipStream_t stream)
{
    const float* t1 = (const float*)d_in[0];
    const float* t2 = (const float*)d_in[1];
    float* out = (float*)d_out;

    char* ws = (char*)d_ws;
    unsigned short* t1n  = (unsigned short*)ws;                                   // 8 MB
    unsigned short* t2n  = (unsigned short*)(ws + (size_t)NROW * KDIM * 2);       // 8 MB
    unsigned short* skew = (unsigned short*)(ws + (size_t)16 * 1024 * 1024);      // 34.1 MB
    unsigned long long* ring = (unsigned long long*)(ws + (size_t)52 * 1024 * 1024);
    // ring: segs 0..15 real, seg 16 = dummy-INF for WG0, then 16x64 garb slots

    hipMemsetAsync(ring, 0, (size_t)NWG * NROW * 8, stream);
    ring_init<<<NROW / 256, 256, 0, stream>>>(ring);
    normalize_bf16<<<2 * NROW, 256, 0, stream>>>(t1, t2, t1n, t2n);
    gemm_cost<<<dim3(NCOL / BM, NROW / BM), 256, 0, stream>>>(t1n, t2n, skew);
    dtw_systolic<<<NWG, 64, 0, stream>>>(skew, ring, out);
}